// Round 4
// baseline (468.877 us; speedup 1.0000x reference)
//
#include <hip/hip_runtime.h>

// B=32, S1=S2=14, NC=2, DC=16, F=32, I=8
// rows = 200704, each row an F x I = 32 x 8 tile; de = row & 31 picks the
// (d,e) weight slice. Outputs: [C | U_hat_I], each rows*256 fp32.
//
// v4: DRAM-locality layout. Each wave owns 98 CONSECUTIVE rows (200704 =
// 2048 waves * 98 exactly), so its two output streams (C and U_hat_I) are
// strictly sequential ~100 KB runs -> DRAM row-buffer friendly (the fill
// kernel hits 6.2 TB/s with exactly this stream shape; the old stride-8192
// mapping made 16K scattered 1KB-granule streams and sat at 2.6 TB/s).
// Consequence: de = row & 31 varies per row, so all 32 weight slices are
// staged in LDS (66 KB/block; 2 blocks/CU = 133 KB <= 160 KB).
//
// Lane layout (unchanged from v3): lane owns two float2 slots per row:
//   oA = 2*lane       -> (f = lane>>2,      i = 2*(lane&3) + {0,1})
//   oB = 2*lane + 128 -> (f = lane>>2 + 16, same i pair)
// f-reductions: 4 shuffle rounds (xor 4,8,16,32) over the 16-lane i-group.
#define N_ROWS      200704
#define ROW_ELEMS   256
#define C_ELEMS     51380224LL
#define BLOCKS      512
#define WAVES_PER_BLOCK 4
#define TOTAL_WAVES (BLOCKS * WAVES_PER_BLOCK)   // 2048
#define ROWS_PER_WAVE (N_ROWS / TOTAL_WAVES)     // 98, exact (no tail)

__global__ __launch_bounds__(256) void mhsa_softmax_kernel(
    const float* __restrict__ U_hat,     // [rows][32]
    const float* __restrict__ W_t,       // [32][32][8]  (de, f, i)
    const float* __restrict__ W_affine,  // [32][32][8]
    float* __restrict__ out)             // [C | U_hat_I]
{
    __shared__ float lwa[32 * ROW_ELEMS];   // W_affine, all 32 de slices
    __shared__ float lwt[32 * ROW_ELEMS];   // W_t
    __shared__ float lwm[32 * 8];           // per-(de,i) max_f of W_t

    const int tid = threadIdx.x;

    // One-time stage of both weight tables (8192 floats each) as float4.
    {
        const float4* wa4 = (const float4*)W_affine;
        const float4* wt4 = (const float4*)W_t;
        float4* la4 = (float4*)lwa;
        float4* lt4 = (float4*)lwt;
#pragma unroll
        for (int k = 0; k < 8; ++k) {       // 2048 float4s / 256 threads
            la4[tid + 256 * k] = wa4[tid + 256 * k];
            lt4[tid + 256 * k] = wt4[tid + 256 * k];
        }
    }
    __syncthreads();
    // Per-(de,i) max over f of W_t. Valid softmax-max because diag >= 0
    // (sum of squares), so max_f(diag*wt) = diag * max_f(wt).
    {
        const int de = tid >> 3, i = tid & 7;   // 256 threads = 32*8 pairs
        float mx = lwt[de * 256 + i];
        for (int f = 1; f < 32; ++f)
            mx = fmaxf(mx, lwt[de * 256 + f * 8 + i]);
        lwm[de * 8 + i] = mx;
    }
    __syncthreads();

    const int lane = tid & 63;
    const int wid  = blockIdx.x * WAVES_PER_BLOCK + (tid >> 6);
    const int q    = lane >> 2;          // fA = q, fB = q + 16
    const int oA   = 2 * lane;           // (fA, i0..i0+1)
    const int oB   = 2 * lane + 128;     // (fB, i0..i0+1)
    const int i0   = 2 * (lane & 3);

    int r = wid * ROWS_PER_WAVE;
    const int rend = r + ROWS_PER_WAVE;

    // Depth-1 prefetch of this lane's two U_hat words.
    float uA, uB;
    {
        const float* uh = U_hat + (long long)r * 32;
        uA = uh[q];
        uB = uh[q + 16];
    }

    for (; r < rend; ++r) {
        const int rp = (r + 1 < rend) ? r + 1 : r;      // clamped prefetch
        const float* uhn = U_hat + (long long)rp * 32;
        const float uAn = uhn[q];
        const float uBn = uhn[q + 16];

        const int de = r & 31;                           // wave-uniform
        const float* wab = lwa + de * ROW_ELEMS;
        const float* wtb = lwt + de * ROW_ELEMS;
        const float2 wavA = *(const float2*)(wab + oA);  // ds_read_b64 x5,
        const float2 wavB = *(const float2*)(wab + oB);  // 2-way bank alias
        const float2 wtvA = *(const float2*)(wtb + oA);  // (free on CDNA4)
        const float2 wtvB = *(const float2*)(wtb + oB);
        const float2 wtm  = *(const float2*)(lwm + de * 8 + i0);

        float* outC = out + (long long)r * ROW_ELEMS;
        float* outU = out + C_ELEMS + (long long)r * ROW_ELEMS;

        // U_hat_I = u * W_affine
        float2 uhiA, uhiB;
        uhiA.x = uA * wavA.x;  uhiA.y = uA * wavA.y;
        uhiB.x = uB * wavB.x;  uhiB.y = uB * wavB.y;
        *(float2*)(outU + oA) = uhiA;
        *(float2*)(outU + oB) = uhiB;

        // diag[i] = sum_f uhi^2 / 4
        float p0 = fmaf(uhiA.x, uhiA.x, uhiB.x * uhiB.x);
        float p1 = fmaf(uhiA.y, uhiA.y, uhiB.y * uhiB.y);
#pragma unroll
        for (int msk = 4; msk <= 32; msk <<= 1) {
            p0 += __shfl_xor(p0, msk);
            p1 += __shfl_xor(p1, msk);
        }
        const float d0 = p0 * 0.25f;       // / sqrt(16)
        const float d1 = p1 * 0.25f;
        const float m0 = d0 * wtm.x;       // exact softmax max per i
        const float m1 = d1 * wtm.y;

        const float eAx = __expf(fmaf(d0, wtvA.x, -m0));
        const float eAy = __expf(fmaf(d1, wtvA.y, -m1));
        const float eBx = __expf(fmaf(d0, wtvB.x, -m0));
        const float eBy = __expf(fmaf(d1, wtvB.y, -m1));

        float s0 = eAx + eBx;
        float s1 = eAy + eBy;
#pragma unroll
        for (int msk = 4; msk <= 32; msk <<= 1) {
            s0 += __shfl_xor(s0, msk);
            s1 += __shfl_xor(s1, msk);
        }
        const float inv0 = __builtin_amdgcn_rcpf(s0);   // s in (0,32], safe
        const float inv1 = __builtin_amdgcn_rcpf(s1);

        float2 cA, cB;
        cA.x = eAx * inv0;  cA.y = eAy * inv1;
        cB.x = eBx * inv0;  cB.y = eBy * inv1;
        *(float2*)(outC + oA) = cA;
        *(float2*)(outC + oB) = cB;

        uA = uAn;
        uB = uBn;
    }
}

extern "C" void kernel_launch(void* const* d_in, const int* in_sizes, int n_in,
                              void* d_out, int out_size, void* d_ws, size_t ws_size,
                              hipStream_t stream) {
    const float* U_hat    = (const float*)d_in[0];
    const float* W_t      = (const float*)d_in[1];
    const float* W_affine = (const float*)d_in[2];
    float* out = (float*)d_out;

    mhsa_softmax_kernel<<<BLOCKS, 256, 0, stream>>>(U_hat, W_t, W_affine, out);
}